// Round 4
// baseline (153.908 us; speedup 1.0000x reference)
//
#include <hip/hip_runtime.h>
#include <math.h>

// Problem constants (from reference)
#define V_SZ 100000
#define D_SZ 128
#define B_SZ 4096
#define NEG_SZ 5
#define L_SZ 6
#define NSLOT 64
#define SCALE 1099511627776.0   // 2^40 fixed-point scale for deterministic int64 accumulation

__device__ __forceinline__ float log_sigmoid(float x) {
    // stable: log_sigmoid(x) = min(x, 0) - log1p(exp(-|x|))
    float ax = fabsf(x);
    return fminf(x, 0.0f) - log1pf(__expf(-ax));
}

__device__ __forceinline__ float wave_reduce_sum(float v) {
    #pragma unroll
    for (int off = 32; off > 0; off >>= 1) v += __shfl_xor(v, off);
    return v;
}

// One BLOCK per batch element b (grid = 4096, 4 waves/block).
// Phrases 0..6 of b:  p=0 -> embed_u, p=1 -> embed_v, p>=2 -> neg p-2.
// Wave w pools phrases {w, w+3} (phrase 3 pooled twice; benign duplicate).
// Gathers are float4 (16B/lane): lanes 0-31 fetch item 2j, lanes 32-63 item
// 2j+1 -> 3 gathers per phrase. All gathers unconditional (padding indices
// are valid vocab ids); ragged mask applied at accumulation.
// Finish: wave 0 computes all 6 dots, converts loss to int64 fixed-point,
// atomicAdds into ws slot (deterministic: integer adds are exact and
// order-independent; atomics are XCD-coherent). Last block sums the slots.
__global__ __launch_bounds__(256) void skipgram_fused_kernel(
    const float* __restrict__ u_emb,
    const float* __restrict__ v_emb,
    const int* __restrict__ pos_u_idx,
    const int* __restrict__ pos_u_len,
    const int* __restrict__ pos_v_idx,
    const int* __restrict__ pos_v_len,
    const int* __restrict__ neg_v_idx,
    const int* __restrict__ neg_v_len,
    unsigned long long* __restrict__ slots,   // ws: NSLOT ull accumulators + 1 u32 counter
    float* __restrict__ out)
{
    __shared__ float lds[7 * D_SZ];

    const int b    = blockIdx.x;
    const int wave = threadIdx.x >> 6;
    const int lane = threadIdx.x & 63;
    const int half = lane >> 5;          // 0: items 0,2,4 ; 1: items 1,3,5
    const int dof  = (lane & 31) * 4;    // 4 dims per lane within a row

    // ---- phrase descriptors (wave-uniform) ----
    const int* idxp[2];
    const float* tab[2];
    int n[2], p[2];
    #pragma unroll
    for (int q = 0; q < 2; ++q) {
        const int pp = wave + 3 * q;     // wave0:{0,3} w1:{1,4} w2:{2,5} w3:{3,6}
        p[q] = pp;
        if (pp == 0) {
            idxp[q] = pos_u_idx + b * L_SZ; tab[q] = u_emb; n[q] = pos_u_len[b] + 1;
        } else if (pp == 1) {
            idxp[q] = pos_v_idx + b * L_SZ; tab[q] = v_emb; n[q] = pos_v_len[b] + 1;
        } else {
            const int m = b * NEG_SZ + pp - 2;
            idxp[q] = neg_v_idx + m * L_SZ; tab[q] = v_emb; n[q] = neg_v_len[m] + 1;
        }
        n[q] = __builtin_amdgcn_readfirstlane(n[q]);   // wave-uniform -> SGPR
    }

    // ---- all 12 indices (wave-uniform; force to SGPR so gather addresses
    //      become scalar-base + dof voffset) ----
    int id[2][L_SZ];
    #pragma unroll
    for (int q = 0; q < 2; ++q)
        #pragma unroll
        for (int l = 0; l < L_SZ; ++l)
            id[q][l] = __builtin_amdgcn_readfirstlane(idxp[q][l]);

    // ---- 6 unconditional float4 row-gathers (2 rows per instruction) ----
    float4 r[2][3];
    #pragma unroll
    for (int q = 0; q < 2; ++q)
        #pragma unroll
        for (int j = 0; j < 3; ++j) {
            const int idx = half ? id[q][2 * j + 1] : id[q][2 * j];
            r[q][j] = *reinterpret_cast<const float4*>(
                &tab[q][(size_t)idx * D_SZ + dof]);
        }

    // ---- masked accumulate, combine halves, scale, store to LDS ----
    #pragma unroll
    for (int q = 0; q < 2; ++q) {
        float4 a = make_float4(0.f, 0.f, 0.f, 0.f);
        #pragma unroll
        for (int j = 0; j < 3; ++j) {
            const bool valid = (2 * j + half) < n[q];
            a.x += valid ? r[q][j].x : 0.f;
            a.y += valid ? r[q][j].y : 0.f;
            a.z += valid ? r[q][j].z : 0.f;
            a.w += valid ? r[q][j].w : 0.f;
        }
        a.x += __shfl_xor(a.x, 32);
        a.y += __shfl_xor(a.y, 32);
        a.z += __shfl_xor(a.z, 32);
        a.w += __shfl_xor(a.w, 32);
        const float inv = 1.0f / (float)n[q];
        a.x *= inv; a.y *= inv; a.z *= inv; a.w *= inv;
        if (lane < 32)
            *reinterpret_cast<float4*>(&lds[p[q] * D_SZ + dof]) = a;
    }
    __syncthreads();

    // ---- wave 0: all 6 dots + loss + global accumulation ----
    if (wave == 0) {
        const float2 eu = *reinterpret_cast<const float2*>(&lds[0 * D_SZ + 2 * lane]);
        float s[6];
        #pragma unroll
        for (int k = 0; k < 6; ++k) {
            const float2 vp = *reinterpret_cast<const float2*>(
                &lds[(k + 1) * D_SZ + 2 * lane]);
            s[k] = eu.x * vp.x + eu.y * vp.y;
        }
        #pragma unroll
        for (int k = 0; k < 6; ++k) s[k] = wave_reduce_sum(s[k]);

        if (lane == 0) {
            float loss = log_sigmoid(s[0]);           // positive pair
            #pragma unroll
            for (int k = 1; k < 6; ++k) loss += log_sigmoid(-s[k]);

            const long long ll = (long long)llrint((double)loss * SCALE);
            atomicAdd(&slots[b & (NSLOT - 1)], (unsigned long long)ll);
            __threadfence();                          // release slot-add before counter-add
            unsigned int* cnt = (unsigned int*)(slots + NSLOT);
            const unsigned int old = atomicAdd(cnt, 1u);
            if (old == gridDim.x - 1) {
                // last block: coherent RMW reads of all slots, fixed-order sum
                long long tot = 0;
                #pragma unroll 4
                for (int i = 0; i < NSLOT; ++i)
                    tot += (long long)atomicAdd(&slots[i], 0ULL);
                out[0] = (float)(-((double)tot / SCALE) / (double)B_SZ);
            }
        }
    }
}

// Fallback (ws unusable): float atomics directly into d_out.
__global__ __launch_bounds__(256) void skipgram_loss_atomic_kernel(
    const float* __restrict__ u_emb,
    const float* __restrict__ v_emb,
    const int* __restrict__ pos_u_idx,
    const int* __restrict__ pos_u_len,
    const int* __restrict__ pos_v_idx,
    const int* __restrict__ pos_v_len,
    const int* __restrict__ neg_v_idx,
    const int* __restrict__ neg_v_len,
    float* __restrict__ out)
{
    __shared__ float lds[7 * D_SZ];
    const int b    = blockIdx.x;
    const int wave = threadIdx.x >> 6;
    const int lane = threadIdx.x & 63;
    const int half = lane >> 5;
    const int dof  = (lane & 31) * 4;

    const int* idxp[2];
    const float* tab[2];
    int n[2], p[2];
    #pragma unroll
    for (int q = 0; q < 2; ++q) {
        const int pp = wave + 3 * q;
        p[q] = pp;
        if (pp == 0) {
            idxp[q] = pos_u_idx + b * L_SZ; tab[q] = u_emb; n[q] = pos_u_len[b] + 1;
        } else if (pp == 1) {
            idxp[q] = pos_v_idx + b * L_SZ; tab[q] = v_emb; n[q] = pos_v_len[b] + 1;
        } else {
            const int m = b * NEG_SZ + pp - 2;
            idxp[q] = neg_v_idx + m * L_SZ; tab[q] = v_emb; n[q] = neg_v_len[m] + 1;
        }
    }
    int id[2][L_SZ];
    #pragma unroll
    for (int q = 0; q < 2; ++q)
        #pragma unroll
        for (int l = 0; l < L_SZ; ++l) id[q][l] = idxp[q][l];
    float4 r[2][3];
    #pragma unroll
    for (int q = 0; q < 2; ++q)
        #pragma unroll
        for (int j = 0; j < 3; ++j) {
            const int idx = half ? id[q][2 * j + 1] : id[q][2 * j];
            r[q][j] = *reinterpret_cast<const float4*>(&tab[q][(size_t)idx * D_SZ + dof]);
        }
    #pragma unroll
    for (int q = 0; q < 2; ++q) {
        float4 a = make_float4(0.f, 0.f, 0.f, 0.f);
        #pragma unroll
        for (int j = 0; j < 3; ++j) {
            const bool valid = (2 * j + half) < n[q];
            a.x += valid ? r[q][j].x : 0.f;
            a.y += valid ? r[q][j].y : 0.f;
            a.z += valid ? r[q][j].z : 0.f;
            a.w += valid ? r[q][j].w : 0.f;
        }
        a.x += __shfl_xor(a.x, 32);
        a.y += __shfl_xor(a.y, 32);
        a.z += __shfl_xor(a.z, 32);
        a.w += __shfl_xor(a.w, 32);
        const float inv = 1.0f / (float)n[q];
        a.x *= inv; a.y *= inv; a.z *= inv; a.w *= inv;
        if (lane < 32)
            *reinterpret_cast<float4*>(&lds[p[q] * D_SZ + dof]) = a;
    }
    __syncthreads();
    if (wave == 0) {
        const float2 eu = *reinterpret_cast<const float2*>(&lds[2 * lane]);
        float s[6];
        #pragma unroll
        for (int k = 0; k < 6; ++k) {
            const float2 vp = *reinterpret_cast<const float2*>(&lds[(k + 1) * D_SZ + 2 * lane]);
            s[k] = eu.x * vp.x + eu.y * vp.y;
        }
        #pragma unroll
        for (int k = 0; k < 6; ++k) s[k] = wave_reduce_sum(s[k]);
        if (lane == 0) {
            float loss = log_sigmoid(s[0]);
            #pragma unroll
            for (int k = 1; k < 6; ++k) loss += log_sigmoid(-s[k]);
            atomicAdd(out, -loss / (float)B_SZ);
        }
    }
}

extern "C" void kernel_launch(void* const* d_in, const int* in_sizes, int n_in,
                              void* d_out, int out_size, void* d_ws, size_t ws_size,
                              hipStream_t stream) {
    const float* u_emb     = (const float*)d_in[0];
    const float* v_emb     = (const float*)d_in[1];
    const int*   pos_u_idx = (const int*)d_in[2];
    const int*   pos_u_len = (const int*)d_in[3];
    const int*   pos_v_idx = (const int*)d_in[4];
    const int*   pos_v_len = (const int*)d_in[5];
    const int*   neg_v_idx = (const int*)d_in[6];
    const int*   neg_v_len = (const int*)d_in[7];
    float* out = (float*)d_out;

    const size_t need = (size_t)(NSLOT + 1) * sizeof(unsigned long long);
    if (ws_size >= need) {
        unsigned long long* slots = (unsigned long long*)d_ws;
        hipMemsetAsync(d_ws, 0, need, stream);        // zero slots + counter (520 B)
        skipgram_fused_kernel<<<B_SZ, 256, 0, stream>>>(
            u_emb, v_emb, pos_u_idx, pos_u_len, pos_v_idx, pos_v_len,
            neg_v_idx, neg_v_len, slots, out);
    } else {
        hipMemsetAsync(d_out, 0, sizeof(float), stream);
        skipgram_loss_atomic_kernel<<<B_SZ, 256, 0, stream>>>(
            u_emb, v_emb, pos_u_idx, pos_u_len, pos_v_idx, pos_v_len,
            neg_v_idx, neg_v_len, out);
    }
}

// Round 5
// 32.518 us; speedup vs baseline: 4.7331x; 4.7331x over previous
//
#include <hip/hip_runtime.h>
#include <math.h>

// Problem constants (from reference)
#define V_SZ 100000
#define D_SZ 128
#define B_SZ 4096
#define NEG_SZ 5
#define L_SZ 6

// Deterministic fence-free reduction:
//   level-1: 64 slots, slot = b & 63, each gets exactly 64 packed adds:
//            (1<<48) | (loss+16)*2^37   (value < 2^41, slot sum < 2^47 -> no
//            carry into the count field at bit 48)
//   level-2: one accumulator, 64 packed adds: (1<<56) | slotTotal (< 2^53)
// The finisher at each level is detected from the RETURNED old count field,
// so the data dependency flows through the atomic itself -- no threadfence.
// Integer adds are exact and commutative -> bit-deterministic across replays.
#define FXSCALE 137438953472.0            // 2^37
#define OFFSET  16.0
#define MASK48  ((1ULL << 48) - 1)
#define MASK56  ((1ULL << 56) - 1)

__device__ __forceinline__ float log_sigmoid(float x) {
    // stable: log_sigmoid(x) = min(x, 0) - log1p(exp(-|x|))
    float ax = fabsf(x);
    return fminf(x, 0.0f) - log1pf(__expf(-ax));
}

__device__ __forceinline__ float wave_reduce_sum(float v) {
    #pragma unroll
    for (int off = 32; off > 0; off >>= 1) v += __shfl_xor(v, off);
    return v;
}

// One BLOCK per batch element b (grid = 4096, 4 waves/block).
// Phrases 0..6 of b:  p=0 -> embed_u, p=1 -> embed_v, p>=2 -> neg p-2.
// Wave w pools phrases {w, w+3} (phrase 3 pooled twice; benign duplicate).
// Gathers are float4 (16B/lane): lanes 0-31 fetch item 2j, lanes 32-63 item
// 2j+1 -> 3 gathers per phrase. All gathers unconditional (padding indices
// are valid vocab ids); ragged mask applied at accumulation.
__global__ __launch_bounds__(256) void skipgram_fused_kernel(
    const float* __restrict__ u_emb,
    const float* __restrict__ v_emb,
    const int* __restrict__ pos_u_idx,
    const int* __restrict__ pos_u_len,
    const int* __restrict__ pos_v_idx,
    const int* __restrict__ pos_v_len,
    const int* __restrict__ neg_v_idx,
    const int* __restrict__ neg_v_len,
    unsigned long long* __restrict__ slots,   // ws: 64 level-1 + 1 level-2
    float* __restrict__ out)
{
    __shared__ float lds[7 * D_SZ];

    const int b    = blockIdx.x;
    const int wave = threadIdx.x >> 6;
    const int lane = threadIdx.x & 63;
    const int half = lane >> 5;          // 0: items 0,2,4 ; 1: items 1,3,5
    const int dof  = (lane & 31) * 4;    // 4 dims per lane within a row

    // ---- phrase descriptors (wave-uniform) ----
    const int* idxp[2];
    const float* tab[2];
    int n[2], p[2];
    #pragma unroll
    for (int q = 0; q < 2; ++q) {
        const int pp = wave + 3 * q;     // wave0:{0,3} w1:{1,4} w2:{2,5} w3:{3,6}
        p[q] = pp;
        if (pp == 0) {
            idxp[q] = pos_u_idx + b * L_SZ; tab[q] = u_emb; n[q] = pos_u_len[b] + 1;
        } else if (pp == 1) {
            idxp[q] = pos_v_idx + b * L_SZ; tab[q] = v_emb; n[q] = pos_v_len[b] + 1;
        } else {
            const int m = b * NEG_SZ + pp - 2;
            idxp[q] = neg_v_idx + m * L_SZ; tab[q] = v_emb; n[q] = neg_v_len[m] + 1;
        }
    }

    // ---- all 12 indices (independent, issue early) ----
    int id[2][L_SZ];
    #pragma unroll
    for (int q = 0; q < 2; ++q)
        #pragma unroll
        for (int l = 0; l < L_SZ; ++l) id[q][l] = idxp[q][l];

    // ---- 6 unconditional float4 row-gathers (2 rows per instruction) ----
    float4 r[2][3];
    #pragma unroll
    for (int q = 0; q < 2; ++q)
        #pragma unroll
        for (int j = 0; j < 3; ++j) {
            const int idx = half ? id[q][2 * j + 1] : id[q][2 * j];
            r[q][j] = *reinterpret_cast<const float4*>(
                &tab[q][(size_t)idx * D_SZ + dof]);
        }

    // ---- masked accumulate, combine halves, scale, store to LDS ----
    #pragma unroll
    for (int q = 0; q < 2; ++q) {
        float4 a = make_float4(0.f, 0.f, 0.f, 0.f);
        #pragma unroll
        for (int j = 0; j < 3; ++j) {
            const bool valid = (2 * j + half) < n[q];
            a.x += valid ? r[q][j].x : 0.f;
            a.y += valid ? r[q][j].y : 0.f;
            a.z += valid ? r[q][j].z : 0.f;
            a.w += valid ? r[q][j].w : 0.f;
        }
        a.x += __shfl_xor(a.x, 32);
        a.y += __shfl_xor(a.y, 32);
        a.z += __shfl_xor(a.z, 32);
        a.w += __shfl_xor(a.w, 32);
        const float inv = 1.0f / (float)n[q];
        a.x *= inv; a.y *= inv; a.z *= inv; a.w *= inv;
        if (lane < 32)
            *reinterpret_cast<float4*>(&lds[p[q] * D_SZ + dof]) = a;
    }
    __syncthreads();

    // ---- wave 0: all 6 dots + loss + fence-free packed reduction ----
    if (wave == 0) {
        const float2 eu = *reinterpret_cast<const float2*>(&lds[0 * D_SZ + 2 * lane]);
        float s[6];
        #pragma unroll
        for (int k = 0; k < 6; ++k) {
            const float2 vp = *reinterpret_cast<const float2*>(
                &lds[(k + 1) * D_SZ + 2 * lane]);
            s[k] = eu.x * vp.x + eu.y * vp.y;
        }
        #pragma unroll
        for (int k = 0; k < 6; ++k) s[k] = wave_reduce_sum(s[k]);

        if (lane == 0) {
            float loss = log_sigmoid(s[0]);           // positive pair
            #pragma unroll
            for (int k = 1; k < 6; ++k) loss += log_sigmoid(-s[k]);
            loss = fmaxf(loss, -15.9f);               // pack-range safety

            // level 1: slot b & 63 (exactly 64 contributors per slot)
            const unsigned long long pack =
                (1ULL << 48) +
                (unsigned long long)llrint(((double)loss + OFFSET) * FXSCALE);
            const unsigned long long old1 = atomicAdd(&slots[b & 63], pack);
            if ((old1 >> 48) == 63) {
                // slot finisher: total flows through the returned value
                const unsigned long long v1 = (old1 + pack) & MASK48;
                const unsigned long long pack2 = (1ULL << 56) + v1;
                const unsigned long long old2 = atomicAdd(&slots[64], pack2);
                if ((old2 >> 56) == 63) {
                    const unsigned long long tot = (old2 + pack2) & MASK56;
                    const double sum_loss =
                        (double)tot / FXSCALE - OFFSET * (double)B_SZ;
                    out[0] = (float)(-sum_loss / (double)B_SZ);
                }
            }
        }
    }
}

// Fallback (ws unusable): float atomics directly into d_out.
__global__ __launch_bounds__(256) void skipgram_loss_atomic_kernel(
    const float* __restrict__ u_emb,
    const float* __restrict__ v_emb,
    const int* __restrict__ pos_u_idx,
    const int* __restrict__ pos_u_len,
    const int* __restrict__ pos_v_idx,
    const int* __restrict__ pos_v_len,
    const int* __restrict__ neg_v_idx,
    const int* __restrict__ neg_v_len,
    float* __restrict__ out)
{
    __shared__ float lds[7 * D_SZ];
    const int b    = blockIdx.x;
    const int wave = threadIdx.x >> 6;
    const int lane = threadIdx.x & 63;
    const int half = lane >> 5;
    const int dof  = (lane & 31) * 4;

    const int* idxp[2];
    const float* tab[2];
    int n[2], p[2];
    #pragma unroll
    for (int q = 0; q < 2; ++q) {
        const int pp = wave + 3 * q;
        p[q] = pp;
        if (pp == 0) {
            idxp[q] = pos_u_idx + b * L_SZ; tab[q] = u_emb; n[q] = pos_u_len[b] + 1;
        } else if (pp == 1) {
            idxp[q] = pos_v_idx + b * L_SZ; tab[q] = v_emb; n[q] = pos_v_len[b] + 1;
        } else {
            const int m = b * NEG_SZ + pp - 2;
            idxp[q] = neg_v_idx + m * L_SZ; tab[q] = v_emb; n[q] = neg_v_len[m] + 1;
        }
    }
    int id[2][L_SZ];
    #pragma unroll
    for (int q = 0; q < 2; ++q)
        #pragma unroll
        for (int l = 0; l < L_SZ; ++l) id[q][l] = idxp[q][l];
    float4 r[2][3];
    #pragma unroll
    for (int q = 0; q < 2; ++q)
        #pragma unroll
        for (int j = 0; j < 3; ++j) {
            const int idx = half ? id[q][2 * j + 1] : id[q][2 * j];
            r[q][j] = *reinterpret_cast<const float4*>(&tab[q][(size_t)idx * D_SZ + dof]);
        }
    #pragma unroll
    for (int q = 0; q < 2; ++q) {
        float4 a = make_float4(0.f, 0.f, 0.f, 0.f);
        #pragma unroll
        for (int j = 0; j < 3; ++j) {
            const bool valid = (2 * j + half) < n[q];
            a.x += valid ? r[q][j].x : 0.f;
            a.y += valid ? r[q][j].y : 0.f;
            a.z += valid ? r[q][j].z : 0.f;
            a.w += valid ? r[q][j].w : 0.f;
        }
        a.x += __shfl_xor(a.x, 32);
        a.y += __shfl_xor(a.y, 32);
        a.z += __shfl_xor(a.z, 32);
        a.w += __shfl_xor(a.w, 32);
        const float inv = 1.0f / (float)n[q];
        a.x *= inv; a.y *= inv; a.z *= inv; a.w *= inv;
        if (lane < 32)
            *reinterpret_cast<float4*>(&lds[p[q] * D_SZ + dof]) = a;
    }
    __syncthreads();
    if (wave == 0) {
        const float2 eu = *reinterpret_cast<const float2*>(&lds[2 * lane]);
        float s[6];
        #pragma unroll
        for (int k = 0; k < 6; ++k) {
            const float2 vp = *reinterpret_cast<const float2*>(&lds[(k + 1) * D_SZ + 2 * lane]);
            s[k] = eu.x * vp.x + eu.y * vp.y;
        }
        #pragma unroll
        for (int k = 0; k < 6; ++k) s[k] = wave_reduce_sum(s[k]);
        if (lane == 0) {
            float loss = log_sigmoid(s[0]);
            #pragma unroll
            for (int k = 1; k < 6; ++k) loss += log_sigmoid(-s[k]);
            atomicAdd(out, -loss / (float)B_SZ);
        }
    }
}

extern "C" void kernel_launch(void* const* d_in, const int* in_sizes, int n_in,
                              void* d_out, int out_size, void* d_ws, size_t ws_size,
                              hipStream_t stream) {
    const float* u_emb     = (const float*)d_in[0];
    const float* v_emb     = (const float*)d_in[1];
    const int*   pos_u_idx = (const int*)d_in[2];
    const int*   pos_u_len = (const int*)d_in[3];
    const int*   pos_v_idx = (const int*)d_in[4];
    const int*   pos_v_len = (const int*)d_in[5];
    const int*   neg_v_idx = (const int*)d_in[6];
    const int*   neg_v_len = (const int*)d_in[7];
    float* out = (float*)d_out;

    const size_t need = 65 * sizeof(unsigned long long);
    if (ws_size >= need) {
        unsigned long long* slots = (unsigned long long*)d_ws;
        hipMemsetAsync(d_ws, 0, need, stream);        // zero 65 slots (520 B)
        skipgram_fused_kernel<<<B_SZ, 256, 0, stream>>>(
            u_emb, v_emb, pos_u_idx, pos_u_len, pos_v_idx, pos_v_len,
            neg_v_idx, neg_v_len, slots, out);
    } else {
        hipMemsetAsync(d_out, 0, sizeof(float), stream);
        skipgram_loss_atomic_kernel<<<B_SZ, 256, 0, stream>>>(
            u_emb, v_emb, pos_u_idx, pos_u_len, pos_v_idx, pos_v_len,
            neg_v_idx, neg_v_len, out);
    }
}

// Round 6
// 22.484 us; speedup vs baseline: 6.8451x; 1.4462x over previous
//
#include <hip/hip_runtime.h>

// Problem constants (from reference)
#define V_SZ 100000
#define D_SZ 128
#define B_SZ 4096
#define NEG_SZ 5
#define L_SZ 6

__device__ __forceinline__ float log_sigmoid(float x) {
    // stable: log_sigmoid(x) = min(x,0) - log(1 + exp(-|x|))
    // fast hw transcendentals: error ~1e-6, far under the 8e-2 threshold
    return fminf(x, 0.0f) - __logf(1.0f + __expf(-fabsf(x)));
}

__device__ __forceinline__ float wave_reduce_sum(float v) {
    #pragma unroll
    for (int off = 32; off > 0; off >>= 1) v += __shfl_xor(v, off);
    return v;
}

// TWO batch elements per block (grid = B/2 = 2048, 4 waves of 64).
// Per b, phrase-slots 0..7: p=0 -> embed_u, p=1 -> embed_v, p=2..6 -> negs
// 0..4, p=7 -> duplicate of p=3 (benign, same data, distinct LDS slot).
// Wave w pools 4 phrases: (b0, w), (b0, w+4), (b1, w), (b1, w+4)
//   -> 12 float4 row-gathers in flight per wave (2 rows per instruction:
//      lanes 0-31 fetch item 2j, lanes 32-63 item 2j+1).
// All gathers unconditional (padding indices are valid vocab ids); ragged
// mask applied at accumulation. Epilogue: wave 0 finishes b0, wave 1
// finishes b1 (6 dots from LDS + log-sigmoids), plain store to per_b[].
__global__ __launch_bounds__(256) void skipgram_loss_kernel(
    const float* __restrict__ u_emb,
    const float* __restrict__ v_emb,
    const int* __restrict__ pos_u_idx,
    const int* __restrict__ pos_u_len,
    const int* __restrict__ pos_v_idx,
    const int* __restrict__ pos_v_len,
    const int* __restrict__ neg_v_idx,
    const int* __restrict__ neg_v_len,
    float* __restrict__ per_b)
{
    __shared__ float lds[2][8][D_SZ];   // 8 KiB

    const int b0   = blockIdx.x * 2;
    const int wave = threadIdx.x >> 6;
    const int lane = threadIdx.x & 63;
    const int half = lane >> 5;          // 0: items 0,2,4 ; 1: items 1,3,5
    const int dof  = (lane & 31) * 4;    // 4 dims per lane within a row

    // ---- 4 phrase descriptors (wave-uniform) ----
    const int* idxp[4];
    const float* tab[4];
    int n[4], sb[4], sp[4];
    #pragma unroll
    for (int q = 0; q < 4; ++q) {
        const int bb = q >> 1;                 // 0,0,1,1
        const int pp = wave + 4 * (q & 1);     // w, w+4
        const int b  = b0 + bb;
        const int eff = (pp == 7) ? 3 : pp;    // slot 7 duplicates neg #1
        sb[q] = bb; sp[q] = pp;
        if (eff == 0) {
            idxp[q] = pos_u_idx + b * L_SZ; tab[q] = u_emb; n[q] = pos_u_len[b] + 1;
        } else if (eff == 1) {
            idxp[q] = pos_v_idx + b * L_SZ; tab[q] = v_emb; n[q] = pos_v_len[b] + 1;
        } else {
            const int m = b * NEG_SZ + (eff - 2);
            idxp[q] = neg_v_idx + m * L_SZ; tab[q] = v_emb; n[q] = neg_v_len[m] + 1;
        }
        n[q] = __builtin_amdgcn_readfirstlane(n[q]);
    }

    // ---- all 24 indices (wave-uniform -> SGPR, issue early) ----
    int id[4][L_SZ];
    #pragma unroll
    for (int q = 0; q < 4; ++q)
        #pragma unroll
        for (int l = 0; l < L_SZ; ++l)
            id[q][l] = __builtin_amdgcn_readfirstlane(idxp[q][l]);

    // ---- 12 unconditional float4 row-gathers (2 rows per instruction) ----
    float4 r[4][3];
    #pragma unroll
    for (int q = 0; q < 4; ++q)
        #pragma unroll
        for (int j = 0; j < 3; ++j) {
            const int idx = half ? id[q][2 * j + 1] : id[q][2 * j];
            r[q][j] = *reinterpret_cast<const float4*>(
                &tab[q][(size_t)idx * D_SZ + dof]);
        }

    // ---- masked accumulate, combine halves, scale, store to LDS ----
    #pragma unroll
    for (int q = 0; q < 4; ++q) {
        float4 a = make_float4(0.f, 0.f, 0.f, 0.f);
        #pragma unroll
        for (int j = 0; j < 3; ++j) {
            const bool valid = (2 * j + half) < n[q];
            a.x += valid ? r[q][j].x : 0.f;
            a.y += valid ? r[q][j].y : 0.f;
            a.z += valid ? r[q][j].z : 0.f;
            a.w += valid ? r[q][j].w : 0.f;
        }
        a.x += __shfl_xor(a.x, 32);
        a.y += __shfl_xor(a.y, 32);
        a.z += __shfl_xor(a.z, 32);
        a.w += __shfl_xor(a.w, 32);
        const float inv = 1.0f / (float)n[q];
        a.x *= inv; a.y *= inv; a.z *= inv; a.w *= inv;
        if (lane < 32)
            *reinterpret_cast<float4*>(&lds[sb[q]][sp[q]][dof]) = a;
    }
    __syncthreads();

    // ---- wave 0 finishes b0, wave 1 finishes b1 ----
    if (wave < 2) {
        const float2 eu = *reinterpret_cast<const float2*>(&lds[wave][0][2 * lane]);
        float s[6];
        #pragma unroll
        for (int k = 0; k < 6; ++k) {
            const float2 vp = *reinterpret_cast<const float2*>(
                &lds[wave][k + 1][2 * lane]);
            s[k] = eu.x * vp.x + eu.y * vp.y;
        }
        #pragma unroll
        for (int k = 0; k < 6; ++k) s[k] = wave_reduce_sum(s[k]);
        if (lane == 0) {
            float loss = log_sigmoid(s[0]);           // positive pair
            #pragma unroll
            for (int k = 1; k < 6; ++k) loss += log_sigmoid(-s[k]);
            per_b[b0 + wave] = loss;
        }
    }
}

__global__ __launch_bounds__(256) void skipgram_reduce_kernel(
    const float* __restrict__ per_b, float* __restrict__ out)
{
    __shared__ float s[4];
    // 4096 floats = 1024 float4 = 4 float4 per thread, fully unrolled
    float acc = 0.0f;
    #pragma unroll
    for (int i = 0; i < 4; ++i) {
        const float4 v = reinterpret_cast<const float4*>(per_b)[
            i * 256 + threadIdx.x];
        acc += (v.x + v.y) + (v.z + v.w);
    }
    acc = wave_reduce_sum(acc);
    const int wave = threadIdx.x >> 6;
    const int lane = threadIdx.x & 63;
    if (lane == 0) s[wave] = acc;
    __syncthreads();
    if (threadIdx.x == 0) {
        out[0] = -(s[0] + s[1] + s[2] + s[3]) / (float)B_SZ;
    }
}

extern "C" void kernel_launch(void* const* d_in, const int* in_sizes, int n_in,
                              void* d_out, int out_size, void* d_ws, size_t ws_size,
                              hipStream_t stream) {
    const float* u_emb     = (const float*)d_in[0];
    const float* v_emb     = (const float*)d_in[1];
    const int*   pos_u_idx = (const int*)d_in[2];
    const int*   pos_u_len = (const int*)d_in[3];
    const int*   pos_v_idx = (const int*)d_in[4];
    const int*   pos_v_len = (const int*)d_in[5];
    const int*   neg_v_idx = (const int*)d_in[6];
    const int*   neg_v_len = (const int*)d_in[7];
    float* out = (float*)d_out;

    float* per_b = (float*)d_ws;   // 16 KiB; ws is far larger
    skipgram_loss_kernel<<<B_SZ / 2, 256, 0, stream>>>(
        u_emb, v_emb, pos_u_idx, pos_u_len, pos_v_idx, pos_v_len,
        neg_v_idx, neg_v_len, per_b);
    skipgram_reduce_kernel<<<1, 256, 0, stream>>>(per_b, out);
}